// Round 1
// baseline (1290.650 us; speedup 1.0000x reference)
//
#include <hip/hip_runtime.h>
#include <cstdint>
#include <cstddef>

#define N_NODES   100000
#define M_PAD     100096   // 782 * 128
#define DIM       256
#define NTYPES    6
#define M_EDGES   400000
#define TOTAL_E   2400000
#define NCNT      600000
#define K_TOT     512      // [hi | lo] split along K
#define SCAN_BLKS 586      // ceil(600000/1024)

typedef __bf16 bf16x8 __attribute__((ext_vector_type(8)));
typedef float  f32x4  __attribute__((ext_vector_type(4)));

static __device__ __forceinline__ unsigned short f32_bf16_rne(float f){
    unsigned u = __float_as_uint(f);
    unsigned r = u + 0x7fffu + ((u >> 16) & 1u);
    return (unsigned short)(r >> 16);
}

static __device__ __forceinline__ uint4 pack8(const unsigned short* h){
    uint4 u;
    u.x = (unsigned)h[0] | ((unsigned)h[1] << 16);
    u.y = (unsigned)h[2] | ((unsigned)h[3] << 16);
    u.z = (unsigned)h[4] | ((unsigned)h[5] << 16);
    u.w = (unsigned)h[6] | ((unsigned)h[7] << 16);
    return u;
}

// ---- A' = [bf16_hi(X) | bf16_lo(X)] rows padded to M_PAD -------------------
__global__ void build_aprime(const float* __restrict__ x, unsigned short* __restrict__ Ap){
    int tid = blockIdx.x * 256 + threadIdx.x;   // M_PAD*256/8 threads
    int idx = tid << 3;
    int row = idx >> 8;
    int k   = idx & 255;
    unsigned short h[8], l[8];
    if (row < N_NODES){
        const float* px = x + (size_t)row * DIM + k;
        #pragma unroll
        for (int j = 0; j < 8; ++j){
            float v = px[j];
            unsigned short hb = f32_bf16_rne(v);
            float hf = __uint_as_float((unsigned)hb << 16);
            h[j] = hb;
            l[j] = f32_bf16_rne(v - hf);
        }
    } else {
        #pragma unroll
        for (int j = 0; j < 8; ++j){ h[j] = 0; l[j] = 0; }
    }
    unsigned short* prow = Ap + (size_t)row * K_TOT;
    *(uint4*)(prow + k)       = pack8(h);
    *(uint4*)(prow + 256 + k) = pack8(l);
}

// ---- B'[t] = [bf16(W_t) | bf16(W_t)]  (256 x 512 per type) -----------------
__global__ void build_bprime(const float* __restrict__ W, unsigned short* __restrict__ Bp){
    int tid = blockIdx.x * 256 + threadIdx.x;   // NTYPES*256*512/8 threads
    int idx = tid << 3;
    int row = idx >> 9;           // 0..1535  (= type*256 + n)
    int k   = idx & (K_TOT - 1);
    int ks  = k & 255;
    const float* pw = W + (size_t)row * 256 + ks;
    unsigned short h[8];
    #pragma unroll
    for (int j = 0; j < 8; ++j) h[j] = f32_bf16_rne(pw[j]);
    *(uint4*)(Bp + (size_t)row * K_TOT + k) = pack8(h);
}

// ---- gating table 2*sigmoid(posemb @ Wp^T + bp), fp64 trig -----------------
__global__ void build_gating(const float* __restrict__ Wp, const float* __restrict__ bp,
                             float* __restrict__ gate){
    __shared__ float semb[256];
    int p = blockIdx.x;     // 0..511
    int t = threadIdx.x;    // 0..255
    if (t < 127){
        double invf = exp(-log(10000.0) * (2.0 * t) / 254.0);
        double a = (double)p * invf;
        semb[t]       = (float)sin(a);
        semb[t + 127] = (float)cos(a);
    } else if (t >= 254){
        semb[t] = 0.0f;
    }
    __syncthreads();
    float z = bp[t];
    const float* wr = Wp + (size_t)t * 256;
    #pragma unroll 4
    for (int kq = 0; kq < 256; ++kq) z += semb[kq] * wr[kq];
    gate[(size_t)p * 256 + t] = 2.0f / (1.0f + expf(-z));
}

// ---- CSR build: histogram -> scan -> scatter -------------------------------
__global__ void hist_kernel(const int* __restrict__ edges, int* __restrict__ cnt){
    int e = blockIdx.x * 256 + threadIdx.x;     // < TOTAL_E exact
    int type = e / M_EDGES;
    int tgt = edges[(size_t)e * 2 + 1];
    atomicAdd(cnt + type * N_NODES + tgt, 1);
}

__global__ void scan1_kernel(const int* __restrict__ cnt, int* __restrict__ partial,
                             int* __restrict__ bsum){
    __shared__ int lds[256];
    int t = threadIdx.x;
    int base = blockIdx.x * 1024 + t * 4;
    int v[4]; int s = 0;
    #pragma unroll
    for (int j = 0; j < 4; ++j){ int idx = base + j; v[j] = (idx < NCNT) ? cnt[idx] : 0; s += v[j]; }
    lds[t] = s; __syncthreads();
    for (int d = 1; d < 256; d <<= 1){
        int xv = (t >= d) ? lds[t - d] : 0;
        __syncthreads();
        lds[t] += xv;
        __syncthreads();
    }
    int run = (t > 0) ? lds[t - 1] : 0;
    #pragma unroll
    for (int j = 0; j < 4; ++j){ int idx = base + j; if (idx < NCNT) partial[idx] = run; run += v[j]; }
    if (t == 255) bsum[blockIdx.x] = run;
}

__global__ void scan2_kernel(const int* __restrict__ bsum, int* __restrict__ ssum){
    __shared__ int lds[256];
    int t = threadIdx.x;
    int base = t * 4;
    int v[4]; int s = 0;
    #pragma unroll
    for (int j = 0; j < 4; ++j){ int idx = base + j; v[j] = (idx < SCAN_BLKS) ? bsum[idx] : 0; s += v[j]; }
    lds[t] = s; __syncthreads();
    for (int d = 1; d < 256; d <<= 1){
        int xv = (t >= d) ? lds[t - d] : 0;
        __syncthreads();
        lds[t] += xv;
        __syncthreads();
    }
    int run = (t > 0) ? lds[t - 1] : 0;
    #pragma unroll
    for (int j = 0; j < 4; ++j){ ssum[base + j] = run; run += v[j]; }
}

__global__ void scan3_kernel(int* __restrict__ off_, const int* __restrict__ ssum,
                             int* __restrict__ cursor){
    int idx = blockIdx.x * 256 + threadIdx.x;
    if (idx >= NCNT) return;
    int vv = off_[idx] + ssum[idx >> 10];
    off_[idx] = vv;
    cursor[idx] = vv;
}

__global__ void scatter_kernel(const int* __restrict__ edges, const int* __restrict__ posl,
                               int* __restrict__ cursor, int* __restrict__ srcs,
                               int* __restrict__ poss){
    int e = blockIdx.x * 256 + threadIdx.x;     // < TOTAL_E exact
    int type = e / M_EDGES;
    int src = edges[(size_t)e * 2];
    int tgt = edges[(size_t)e * 2 + 1];
    int p = atomicAdd(cursor + type * N_NODES + tgt, 1);
    srcs[p] = src;
    poss[p] = posl[e];
}

// ---- bf16 NT GEMM: C(M_PAD x 256) = A'(M_PAD x 512) * B'(256 x 512)^T + bias
// tile 128x256, BK=64, 8 waves; XOR-swizzled LDS (16B slots), reg staging.
__global__ __launch_bounds__(512, 4) void gemm_nt(
        const unsigned short* __restrict__ Ap,
        const unsigned short* __restrict__ Bp,
        const float* __restrict__ bias,
        float* __restrict__ C)
{
    __shared__ __align__(16) unsigned short sA[128 * 64];
    __shared__ __align__(16) unsigned short sB[256 * 64];
    const int tid  = threadIdx.x;
    const int lane = tid & 63;
    const int wid  = tid >> 6;
    const int wr   = wid >> 2;   // 0..1
    const int wc   = wid & 3;    // 0..3
    const size_t m0 = (size_t)blockIdx.x * 128;

    f32x4 acc[4][4];
    #pragma unroll
    for (int m = 0; m < 4; ++m)
        #pragma unroll
        for (int n = 0; n < 4; ++n)
            acc[m][n] = (f32x4){0.f, 0.f, 0.f, 0.f};

    const int sub = lane >> 3;        // row within 8-row chunk
    const int bib = (lane & 7) << 4;  // byte within 128B row

    for (int kk = 0; kk < 8; ++kk){
        // stage 48KB (A:16 chunks, B:32 chunks of 8rows x 128B); 6 chunks/wave
        #pragma unroll
        for (int ci = 0; ci < 6; ++ci){
            int c = wid * 6 + ci;
            const unsigned short* grow;
            unsigned short* lrow;
            int r;
            if (c < 16){
                r = (c << 3) + sub;                     // 0..127
                grow = Ap + (m0 + (size_t)r) * K_TOT;
                lrow = sA + r * 64;
            } else {
                r = ((c - 16) << 3) + sub;              // 0..255
                grow = Bp + (size_t)r * K_TOT;
                lrow = sB + r * 64;
            }
            uint4 v = *(const uint4*)((const char*)grow + (kk << 7) + bib);
            int sw = bib ^ ((r & 7) << 4);
            *(uint4*)((char*)lrow + sw) = v;
        }
        __syncthreads();

        #pragma unroll
        for (int ks = 0; ks < 2; ++ks){
            int slot = (ks << 6) + ((lane >> 4) << 4);
            bf16x8 af[4];
            #pragma unroll
            for (int m = 0; m < 4; ++m){
                int rA = (wr << 6) + (m << 4) + (lane & 15);
                af[m] = *(const bf16x8*)((const char*)sA + rA * 128 + (slot ^ ((rA & 7) << 4)));
            }
            #pragma unroll
            for (int n = 0; n < 4; ++n){
                int rB = (wc << 6) + (n << 4) + (lane & 15);
                bf16x8 bfr = *(const bf16x8*)((const char*)sB + rB * 128 + (slot ^ ((rB & 7) << 4)));
                #pragma unroll
                for (int m = 0; m < 4; ++m)
                    acc[m][n] = __builtin_amdgcn_mfma_f32_16x16x32_bf16(af[m], bfr, acc[m][n], 0, 0, 0);
            }
        }
        __syncthreads();
    }

    // epilogue: + bias, store fp32
    #pragma unroll
    for (int n = 0; n < 4; ++n){
        int col = (wc << 6) + (n << 4) + (lane & 15);
        float bv = bias[col];
        #pragma unroll
        for (int m = 0; m < 4; ++m){
            int rowb = (int)m0 + (wr << 6) + (m << 4) + ((lane >> 4) << 2);
            #pragma unroll
            for (int j = 0; j < 4; ++j)
                C[(size_t)(rowb + j) * DIM + col] = acc[m][n][j] + bv;
        }
    }
}

// ---- per-type aggregation: one wave per target node, register accumulate ---
__global__ void aggregate(const float* __restrict__ prop, const float* __restrict__ gate,
                          const int* __restrict__ srcs, const int* __restrict__ poss,
                          const int* __restrict__ offt, const int* __restrict__ cntt,
                          float* __restrict__ out)
{
    int tgt  = blockIdx.x * 4 + (threadIdx.x >> 6);
    int lane = threadIdx.x & 63;
    int n = cntt[tgt];
    if (n == 0) return;
    int base = offt[tgt];
    float4 a = make_float4(0.f, 0.f, 0.f, 0.f);
    for (int e = 0; e < n; ++e){
        int s  = srcs[base + e];
        int pz = poss[base + e];
        float4 pv = *(const float4*)(prop + (size_t)s  * DIM + lane * 4);
        float4 gv = *(const float4*)(gate + (size_t)pz * DIM + lane * 4);
        a.x += pv.x * gv.x; a.y += pv.y * gv.y; a.z += pv.z * gv.z; a.w += pv.w * gv.w;
    }
    float4* op = (float4*)(out + (size_t)tgt * DIM) + lane;
    float4 cur = *op;
    cur.x += a.x; cur.y += a.y; cur.z += a.z; cur.w += a.w;
    *op = cur;
}

// ---- divide by (bincount or 1) + 1e-8 --------------------------------------
__global__ void divide_kernel(const int* __restrict__ cnt, float* __restrict__ out){
    int gid = blockIdx.x * 256 + threadIdx.x;   // < N_NODES*64
    int t = gid >> 6;
    int c = gid & 63;
    int deg = 0;
    #pragma unroll
    for (int i = 0; i < NTYPES; ++i) deg += cnt[i * N_NODES + t];
    float dv = (deg == 0) ? 1.0f : (float)deg;
    float inv = dv + 1e-8f;
    float4* p = (float4*)(out + (size_t)t * DIM) + c;
    float4 v = *p;
    v.x /= inv; v.y /= inv; v.z /= inv; v.w /= inv;
    *p = v;
}

extern "C" void kernel_launch(void* const* d_in, const int* in_sizes, int n_in,
                              void* d_out, int out_size, void* d_ws, size_t ws_size,
                              hipStream_t stream)
{
    const float* x     = (const float*)d_in[0];
    const float* W     = (const float*)d_in[1];
    const float* b     = (const float*)d_in[2];
    const float* Wp    = (const float*)d_in[3];
    const float* bp    = (const float*)d_in[4];
    const int*   edges = (const int*)d_in[5];
    const int*   posl  = (const int*)d_in[6];
    float* out = (float*)d_out;

    char* ws = (char*)d_ws;
    size_t o = 0;
    auto alloc = [&](size_t bytes){ void* p = ws + o; o += (bytes + 255) & ~(size_t)255; return p; };
    unsigned short* Ap   = (unsigned short*)alloc((size_t)M_PAD * K_TOT * 2);
    float*          prop = (float*)alloc((size_t)M_PAD * DIM * 4);
    unsigned short* Bp   = (unsigned short*)alloc((size_t)NTYPES * 256 * K_TOT * 2);
    float*          gate = (float*)alloc((size_t)512 * DIM * 4);
    int* cnt    = (int*)alloc((size_t)NCNT * 4);
    int* off_   = (int*)alloc((size_t)NCNT * 4);
    int* cursor = (int*)alloc((size_t)NCNT * 4);
    int* srcs   = (int*)alloc((size_t)TOTAL_E * 4);
    int* poss   = (int*)alloc((size_t)TOTAL_E * 4);
    int* bsum   = (int*)alloc(1024 * 4);
    int* ssum   = (int*)alloc(1024 * 4);

    hipMemsetAsync(d_out, 0, (size_t)N_NODES * DIM * sizeof(float), stream);
    hipMemsetAsync(cnt, 0, (size_t)NCNT * sizeof(int), stream);

    build_aprime<<<12512, 256, 0, stream>>>(x, Ap);
    build_bprime<<<384, 256, 0, stream>>>(W, Bp);
    build_gating<<<512, 256, 0, stream>>>(Wp, bp, gate);
    hist_kernel<<<9375, 256, 0, stream>>>(edges, cnt);
    scan1_kernel<<<SCAN_BLKS, 256, 0, stream>>>(cnt, off_, bsum);
    scan2_kernel<<<1, 256, 0, stream>>>(bsum, ssum);
    scan3_kernel<<<2344, 256, 0, stream>>>(off_, ssum, cursor);
    scatter_kernel<<<9375, 256, 0, stream>>>(edges, posl, cursor, srcs, poss);

    for (int t = 0; t < NTYPES; ++t){
        gemm_nt<<<782, 512, 0, stream>>>(Ap, Bp + (size_t)t * 256 * K_TOT, b + t * DIM, prop);
        aggregate<<<25000, 256, 0, stream>>>(prop, gate, srcs, poss,
                                             off_ + t * N_NODES, cnt + t * N_NODES, out);
    }
    divide_kernel<<<25000, 256, 0, stream>>>(cnt, out);
}

// Round 2
// 1125.059 us; speedup vs baseline: 1.1472x; 1.1472x over previous
//
#include <hip/hip_runtime.h>
#include <cstdint>
#include <cstddef>

#define N_NODES   100000
#define M_PAD     100096   // 782 * 128
#define DIM       256
#define NTYPES    6
#define M_EDGES   400000
#define TOTAL_E   2400000
#define SCAN_BLKS 98       // ceil(100000/1024)

typedef _Float16 f16x8 __attribute__((ext_vector_type(8)));
typedef _Float16 f16x4 __attribute__((ext_vector_type(4)));
typedef float    f32x4 __attribute__((ext_vector_type(4)));

// ---- A16 = fp16(X), rows padded to M_PAD ----------------------------------
__global__ void build_a16(const float* __restrict__ x, _Float16* __restrict__ Ap){
    int tid = blockIdx.x * 256 + threadIdx.x;   // M_PAD*256/8 threads exact
    int idx = tid << 3;
    int row = idx >> 8;
    int k   = idx & 255;
    f16x8 h;
    if (row < N_NODES){
        const float* px = x + (size_t)row * DIM + k;
        float4 v0 = *(const float4*)px;
        float4 v1 = *(const float4*)(px + 4);
        h[0] = (_Float16)v0.x; h[1] = (_Float16)v0.y; h[2] = (_Float16)v0.z; h[3] = (_Float16)v0.w;
        h[4] = (_Float16)v1.x; h[5] = (_Float16)v1.y; h[6] = (_Float16)v1.z; h[7] = (_Float16)v1.w;
    } else {
        #pragma unroll
        for (int j = 0; j < 8; ++j) h[j] = (_Float16)0.f;
    }
    *(f16x8*)(Ap + (size_t)row * 256 + k) = h;
}

// ---- B16 = fp16(W)  (1536 x 256) ------------------------------------------
__global__ void build_b16(const float* __restrict__ W, _Float16* __restrict__ Bp){
    int tid = blockIdx.x * 256 + threadIdx.x;   // 1536*256/8 threads exact
    int idx = tid << 3;
    const float* pw = W + idx;
    float4 v0 = *(const float4*)pw;
    float4 v1 = *(const float4*)(pw + 4);
    f16x8 h;
    h[0] = (_Float16)v0.x; h[1] = (_Float16)v0.y; h[2] = (_Float16)v0.z; h[3] = (_Float16)v0.w;
    h[4] = (_Float16)v1.x; h[5] = (_Float16)v1.y; h[6] = (_Float16)v1.z; h[7] = (_Float16)v1.w;
    *(f16x8*)(Bp + idx) = h;
}

// ---- gating table 2*sigmoid(posemb @ Wp^T + bp), fp64 trig, fp16 out ------
__global__ void build_gating(const float* __restrict__ Wp, const float* __restrict__ bp,
                             _Float16* __restrict__ gate){
    __shared__ float semb[256];
    int p = blockIdx.x;     // 0..511
    int t = threadIdx.x;    // 0..255
    if (t < 127){
        double invf = exp(-log(10000.0) * (2.0 * t) / 254.0);
        double a = (double)p * invf;
        semb[t]       = (float)sin(a);
        semb[t + 127] = (float)cos(a);
    } else if (t >= 254){
        semb[t] = 0.0f;
    }
    __syncthreads();
    float z = bp[t];
    const float* wr = Wp + (size_t)t * 256;
    #pragma unroll 4
    for (int kq = 0; kq < 256; ++kq) z += semb[kq] * wr[kq];
    gate[(size_t)p * 256 + t] = (_Float16)(2.0f / (1.0f + expf(-z)));
}

// ---- CSR build over tgt only: histogram -> scan -> scatter packed word ----
__global__ void hist_kernel(const int* __restrict__ edges, int* __restrict__ cnt){
    int e = blockIdx.x * 256 + threadIdx.x;     // TOTAL_E exact
    int tgt = edges[(size_t)e * 2 + 1];
    atomicAdd(cnt + tgt, 1);
}

__global__ void scan1_kernel(const int* __restrict__ cnt, int* __restrict__ partial,
                             int* __restrict__ bsum){
    __shared__ int lds[256];
    int t = threadIdx.x;
    int base = blockIdx.x * 1024 + t * 4;
    int v[4]; int s = 0;
    #pragma unroll
    for (int j = 0; j < 4; ++j){ int idx = base + j; v[j] = (idx < N_NODES) ? cnt[idx] : 0; s += v[j]; }
    lds[t] = s; __syncthreads();
    for (int d = 1; d < 256; d <<= 1){
        int xv = (t >= d) ? lds[t - d] : 0;
        __syncthreads();
        lds[t] += xv;
        __syncthreads();
    }
    int run = (t > 0) ? lds[t - 1] : 0;
    #pragma unroll
    for (int j = 0; j < 4; ++j){ int idx = base + j; if (idx < N_NODES) partial[idx] = run; run += v[j]; }
    if (t == 255) bsum[blockIdx.x] = run;
}

__global__ void scan2_kernel(const int* __restrict__ bsum, int* __restrict__ ssum){
    __shared__ int lds[256];
    int t = threadIdx.x;
    int base = t * 4;
    int v[4]; int s = 0;
    #pragma unroll
    for (int j = 0; j < 4; ++j){ int idx = base + j; v[j] = (idx < SCAN_BLKS) ? bsum[idx] : 0; s += v[j]; }
    lds[t] = s; __syncthreads();
    for (int d = 1; d < 256; d <<= 1){
        int xv = (t >= d) ? lds[t - d] : 0;
        __syncthreads();
        lds[t] += xv;
        __syncthreads();
    }
    int run = (t > 0) ? lds[t - 1] : 0;
    #pragma unroll
    for (int j = 0; j < 4; ++j){ ssum[base + j] = run; run += v[j]; }
}

__global__ void scan3_kernel(int* __restrict__ off_, const int* __restrict__ ssum,
                             int* __restrict__ cursor){
    int idx = blockIdx.x * 256 + threadIdx.x;
    if (idx >= N_NODES) return;
    int vv = off_[idx] + ssum[idx >> 10];
    off_[idx] = vv;
    cursor[idx] = vv;
}

__global__ void scatter_kernel(const int* __restrict__ edges, const int* __restrict__ posl,
                               int* __restrict__ cursor, unsigned* __restrict__ packed){
    int e = blockIdx.x * 256 + threadIdx.x;     // TOTAL_E exact
    int type = e / M_EDGES;
    int src = edges[(size_t)e * 2];
    int tgt = edges[(size_t)e * 2 + 1];
    int p = atomicAdd(cursor + tgt, 1);
    packed[p] = (unsigned)src | ((unsigned)posl[e] << 17) | ((unsigned)type << 26);
}

// ---- fp16 NT GEMM: prop_t(M_PAD x 256) = A16(M_PAD x 256) * B_t(256 x 256)^T + b_t
// tile 128x256, BK=64, 8 waves; XOR-swizzled LDS, reg staging; ntypes folded in grid
__global__ __launch_bounds__(512, 4) void gemm_f16(
        const _Float16* __restrict__ Ap,
        const _Float16* __restrict__ Bp,
        const float* __restrict__ bias,
        _Float16* __restrict__ prop,
        int ntypes)
{
    __shared__ __align__(16) _Float16 sA[128 * 64];
    __shared__ __align__(16) _Float16 sB[256 * 64];
    const int bid  = blockIdx.x;
    const int rp   = bid / ntypes;          // row panel
    const int t    = bid - rp * ntypes;     // type
    const int tid  = threadIdx.x;
    const int lane = tid & 63;
    const int wid  = tid >> 6;
    const int wr   = wid >> 2;   // 0..1
    const int wc   = wid & 3;    // 0..3
    const size_t m0 = (size_t)rp * 128;
    const _Float16* Bt = Bp + (size_t)t * 256 * 256;

    f32x4 acc[4][4];
    #pragma unroll
    for (int m = 0; m < 4; ++m)
        #pragma unroll
        for (int n = 0; n < 4; ++n)
            acc[m][n] = (f32x4){0.f, 0.f, 0.f, 0.f};

    const int sub = lane >> 3;        // row within 8-row chunk
    const int bib = (lane & 7) << 4;  // byte within 128B row

    for (int kk = 0; kk < 4; ++kk){
        #pragma unroll
        for (int ci = 0; ci < 6; ++ci){
            int c = wid * 6 + ci;
            const _Float16* grow;
            _Float16* lrow;
            int r;
            if (c < 16){
                r = (c << 3) + sub;                     // 0..127
                grow = Ap + (m0 + (size_t)r) * 256;
                lrow = sA + r * 64;
            } else {
                r = ((c - 16) << 3) + sub;              // 0..255
                grow = Bt + (size_t)r * 256;
                lrow = sB + r * 64;
            }
            uint4 v = *(const uint4*)((const char*)grow + (kk << 7) + bib);
            int sw = bib ^ ((r & 7) << 4);
            *(uint4*)((char*)lrow + sw) = v;
        }
        __syncthreads();

        #pragma unroll
        for (int ks = 0; ks < 2; ++ks){
            int slot = (ks << 6) + ((lane >> 4) << 4);
            f16x8 af[4];
            #pragma unroll
            for (int m = 0; m < 4; ++m){
                int rA = (wr << 6) + (m << 4) + (lane & 15);
                af[m] = *(const f16x8*)((const char*)sA + rA * 128 + (slot ^ ((rA & 7) << 4)));
            }
            #pragma unroll
            for (int n = 0; n < 4; ++n){
                int rB = (wc << 6) + (n << 4) + (lane & 15);
                f16x8 bfr = *(const f16x8*)((const char*)sB + rB * 128 + (slot ^ ((rB & 7) << 4)));
                #pragma unroll
                for (int m = 0; m < 4; ++m)
                    acc[m][n] = __builtin_amdgcn_mfma_f32_16x16x32_f16(af[m], bfr, acc[m][n], 0, 0, 0);
            }
        }
        __syncthreads();
    }

    _Float16* Ct = prop + (size_t)t * M_PAD * 256;
    #pragma unroll
    for (int n = 0; n < 4; ++n){
        int col = (wc << 6) + (n << 4) + (lane & 15);
        float bv = bias[(size_t)t * 256 + col];
        #pragma unroll
        for (int m = 0; m < 4; ++m){
            int rowb = (int)m0 + (wr << 6) + (m << 4) + ((lane >> 4) << 2);
            #pragma unroll
            for (int j = 0; j < 4; ++j)
                Ct[(size_t)(rowb + j) * DIM + col] = (_Float16)(acc[m][n][j] + bv);
        }
    }
}

// ---- aggregation: one wave per target node over ALL its edges -------------
// mode < 0: all-types fused (prop holds 6 buffers), divide fused, plain store
// mode = t: only type t (prop holds 1 buffer), accumulate into out, no divide
__global__ void aggregate(const _Float16* __restrict__ prop, const _Float16* __restrict__ gate,
                          const unsigned* __restrict__ packed,
                          const int* __restrict__ off_, const int* __restrict__ cnt,
                          int mode, float* __restrict__ out)
{
    int tgt  = blockIdx.x * 4 + (threadIdx.x >> 6);
    int lane = threadIdx.x & 63;
    int n = cnt[tgt];
    int base = off_[tgt];
    float4 a = make_float4(0.f, 0.f, 0.f, 0.f);
    int matched = 0;
    for (int e = 0; e < n; ++e){
        unsigned w = packed[base + e];
        int ty = (int)(w >> 26);
        if (mode >= 0 && ty != mode) continue;
        int src = (int)(w & 0x1FFFFu);
        int pz  = (int)((w >> 17) & 0x1FFu);
        size_t prow = (mode >= 0) ? (size_t)src * 256 : ((size_t)ty * M_PAD + (size_t)src) * 256;
        f16x4 pv = *(const f16x4*)(prop + prow + lane * 4);
        f16x4 gv = *(const f16x4*)(gate + (size_t)pz * 256 + lane * 4);
        a.x += (float)pv[0] * (float)gv[0];
        a.y += (float)pv[1] * (float)gv[1];
        a.z += (float)pv[2] * (float)gv[2];
        a.w += (float)pv[3] * (float)gv[3];
        ++matched;
    }
    float4* op = (float4*)(out + (size_t)tgt * DIM) + lane;
    if (mode < 0){
        float inv = ((n == 0) ? 1.0f : (float)n) + 1e-8f;
        float4 r = make_float4(a.x / inv, a.y / inv, a.z / inv, a.w / inv);
        *op = r;
    } else if (matched){
        float4 c = *op;
        c.x += a.x; c.y += a.y; c.z += a.z; c.w += a.w;
        *op = c;
    }
}

// ---- plan-B divide --------------------------------------------------------
__global__ void divide_kernel(const int* __restrict__ cnt, float* __restrict__ out){
    int gid = blockIdx.x * 256 + threadIdx.x;   // N_NODES*64 exact
    int t = gid >> 6;
    int c = gid & 63;
    int deg = cnt[t];
    float dv = (deg == 0) ? 1.0f : (float)deg;
    float inv = dv + 1e-8f;
    float4* p = (float4*)(out + (size_t)t * DIM) + c;
    float4 v = *p;
    v.x /= inv; v.y /= inv; v.z /= inv; v.w /= inv;
    *p = v;
}

extern "C" void kernel_launch(void* const* d_in, const int* in_sizes, int n_in,
                              void* d_out, int out_size, void* d_ws, size_t ws_size,
                              hipStream_t stream)
{
    const float* x     = (const float*)d_in[0];
    const float* W     = (const float*)d_in[1];
    const float* b     = (const float*)d_in[2];
    const float* Wp    = (const float*)d_in[3];
    const float* bp    = (const float*)d_in[4];
    const int*   edges = (const int*)d_in[5];
    const int*   posl  = (const int*)d_in[6];
    float* out = (float*)d_out;

    char* ws = (char*)d_ws;
    size_t o = 0;
    auto alloc = [&](size_t bytes){ void* p = ws + o; o += (bytes + 255) & ~(size_t)255; return p; };

    _Float16* Ap   = (_Float16*)alloc((size_t)M_PAD * 256 * 2);
    _Float16* Bp   = (_Float16*)alloc((size_t)NTYPES * 256 * 256 * 2);
    _Float16* gate = (_Float16*)alloc((size_t)512 * 256 * 2);
    int* cnt    = (int*)alloc((size_t)N_NODES * 4);
    int* off_   = (int*)alloc((size_t)N_NODES * 4);
    int* cursor = (int*)alloc((size_t)N_NODES * 4);
    unsigned* packed = (unsigned*)alloc((size_t)TOTAL_E * 4);
    int* bsum   = (int*)alloc(4096);
    int* ssum   = (int*)alloc(4096);
    size_t common = o;
    size_t planA_total = common + (size_t)NTYPES * M_PAD * 256 * 2 + 256;
    bool planA = (ws_size >= planA_total);
    _Float16* prop = (_Float16*)alloc(planA ? (size_t)NTYPES * M_PAD * 256 * 2
                                            : (size_t)M_PAD * 256 * 2);

    hipMemsetAsync(cnt, 0, (size_t)N_NODES * 4, stream);

    build_a16<<<12512, 256, 0, stream>>>(x, Ap);
    build_b16<<<192, 256, 0, stream>>>(W, Bp);
    build_gating<<<512, 256, 0, stream>>>(Wp, bp, gate);
    hist_kernel<<<9375, 256, 0, stream>>>(edges, cnt);
    scan1_kernel<<<SCAN_BLKS, 256, 0, stream>>>(cnt, off_, bsum);
    scan2_kernel<<<1, 256, 0, stream>>>(bsum, ssum);
    scan3_kernel<<<391, 256, 0, stream>>>(off_, ssum, cursor);
    scatter_kernel<<<9375, 256, 0, stream>>>(edges, posl, cursor, packed);

    if (planA){
        gemm_f16<<<782 * NTYPES, 512, 0, stream>>>(Ap, Bp, b, prop, NTYPES);
        aggregate<<<25000, 256, 0, stream>>>(prop, gate, packed, off_, cnt, -1, out);
    } else {
        hipMemsetAsync(out, 0, (size_t)N_NODES * DIM * 4, stream);
        for (int t = 0; t < NTYPES; ++t){
            gemm_f16<<<782, 512, 0, stream>>>(Ap, Bp + (size_t)t * 256 * 256,
                                              b + (size_t)t * 256, prop, 1);
            aggregate<<<25000, 256, 0, stream>>>(prop, gate, packed, off_, cnt, t, out);
        }
        divide_kernel<<<25000, 256, 0, stream>>>(cnt, out);
    }
}

// Round 3
// 1005.328 us; speedup vs baseline: 1.2838x; 1.1191x over previous
//
#include <hip/hip_runtime.h>
#include <cstdint>
#include <cstddef>

#define N_NODES   100000
#define M_PAD     100096   // 782 * 128
#define DIM       256
#define NTYPES    6
#define M_EDGES   400000
#define TOTAL_E   2400000
#define NCNT      600000   // NTYPES * N_NODES
#define SCAN_BLKS 586      // ceil(NCNT/1024)

typedef _Float16 f16x8 __attribute__((ext_vector_type(8)));
typedef _Float16 f16x4 __attribute__((ext_vector_type(4)));
typedef float    f32x4 __attribute__((ext_vector_type(4)));

// ---- A16 = fp16(X), rows padded to M_PAD ----------------------------------
__global__ void build_a16(const float* __restrict__ x, _Float16* __restrict__ Ap){
    int tid = blockIdx.x * 256 + threadIdx.x;   // M_PAD*256/8 threads exact
    int idx = tid << 3;
    int row = idx >> 8;
    int k   = idx & 255;
    f16x8 h;
    if (row < N_NODES){
        const float* px = x + (size_t)row * DIM + k;
        float4 v0 = *(const float4*)px;
        float4 v1 = *(const float4*)(px + 4);
        h[0] = (_Float16)v0.x; h[1] = (_Float16)v0.y; h[2] = (_Float16)v0.z; h[3] = (_Float16)v0.w;
        h[4] = (_Float16)v1.x; h[5] = (_Float16)v1.y; h[6] = (_Float16)v1.z; h[7] = (_Float16)v1.w;
    } else {
        #pragma unroll
        for (int j = 0; j < 8; ++j) h[j] = (_Float16)0.f;
    }
    *(f16x8*)(Ap + (size_t)row * 256 + k) = h;
}

// ---- B16 = fp16(W)  (1536 x 256) ------------------------------------------
__global__ void build_b16(const float* __restrict__ W, _Float16* __restrict__ Bp){
    int tid = blockIdx.x * 256 + threadIdx.x;   // 1536*256/8 threads exact
    int idx = tid << 3;
    const float* pw = W + idx;
    float4 v0 = *(const float4*)pw;
    float4 v1 = *(const float4*)(pw + 4);
    f16x8 h;
    h[0] = (_Float16)v0.x; h[1] = (_Float16)v0.y; h[2] = (_Float16)v0.z; h[3] = (_Float16)v0.w;
    h[4] = (_Float16)v1.x; h[5] = (_Float16)v1.y; h[6] = (_Float16)v1.z; h[7] = (_Float16)v1.w;
    *(f16x8*)(Bp + idx) = h;
}

// ---- gating table 2*sigmoid(posemb @ Wp^T + bp), fp64 trig, fp16 out ------
__global__ void build_gating(const float* __restrict__ Wp, const float* __restrict__ bp,
                             _Float16* __restrict__ gate){
    __shared__ float semb[256];
    int p = blockIdx.x;     // 0..511
    int t = threadIdx.x;    // 0..255
    if (t < 127){
        double invf = exp(-log(10000.0) * (2.0 * t) / 254.0);
        double a = (double)p * invf;
        semb[t]       = (float)sin(a);
        semb[t + 127] = (float)cos(a);
    } else if (t >= 254){
        semb[t] = 0.0f;
    }
    __syncthreads();
    float z = bp[t];
    const float* wr = Wp + (size_t)t * 256;
    #pragma unroll 4
    for (int kq = 0; kq < 256; ++kq) z += semb[kq] * wr[kq];
    gate[(size_t)p * 256 + t] = (_Float16)(2.0f / (1.0f + expf(-z)));
}

// ---- CSR build over (type,tgt): histogram -> scan -> scatter --------------
__global__ void hist_kernel(const int* __restrict__ edges, int* __restrict__ cnt){
    int e = blockIdx.x * 256 + threadIdx.x;     // TOTAL_E exact
    int type = e / M_EDGES;
    int tgt = edges[(size_t)e * 2 + 1];
    atomicAdd(cnt + type * N_NODES + tgt, 1);
}

__global__ void scan1_kernel(const int* __restrict__ cnt, int* __restrict__ partial,
                             int* __restrict__ bsum){
    __shared__ int lds[256];
    int t = threadIdx.x;
    int base = blockIdx.x * 1024 + t * 4;
    int v[4]; int s = 0;
    #pragma unroll
    for (int j = 0; j < 4; ++j){ int idx = base + j; v[j] = (idx < NCNT) ? cnt[idx] : 0; s += v[j]; }
    lds[t] = s; __syncthreads();
    for (int d = 1; d < 256; d <<= 1){
        int xv = (t >= d) ? lds[t - d] : 0;
        __syncthreads();
        lds[t] += xv;
        __syncthreads();
    }
    int run = (t > 0) ? lds[t - 1] : 0;
    #pragma unroll
    for (int j = 0; j < 4; ++j){ int idx = base + j; if (idx < NCNT) partial[idx] = run; run += v[j]; }
    if (t == 255) bsum[blockIdx.x] = run;
}

__global__ void scan2_kernel(const int* __restrict__ bsum, int* __restrict__ ssum){
    __shared__ int lds[256];
    int t = threadIdx.x;
    int base = t * 4;
    int v[4]; int s = 0;
    #pragma unroll
    for (int j = 0; j < 4; ++j){ int idx = base + j; v[j] = (idx < SCAN_BLKS) ? bsum[idx] : 0; s += v[j]; }
    lds[t] = s; __syncthreads();
    for (int d = 1; d < 256; d <<= 1){
        int xv = (t >= d) ? lds[t - d] : 0;
        __syncthreads();
        lds[t] += xv;
        __syncthreads();
    }
    int run = (t > 0) ? lds[t - 1] : 0;
    #pragma unroll
    for (int j = 0; j < 4; ++j){ ssum[base + j] = run; run += v[j]; }
}

__global__ void scan3_kernel(int* __restrict__ off_, const int* __restrict__ ssum,
                             int* __restrict__ cursor){
    int idx = blockIdx.x * 256 + threadIdx.x;
    if (idx >= NCNT) return;
    int vv = off_[idx] + ssum[idx >> 10];
    off_[idx] = vv;
    cursor[idx] = vv;
}

__global__ void scatter_kernel(const int* __restrict__ edges, const int* __restrict__ posl,
                               int* __restrict__ cursor, unsigned* __restrict__ packed){
    int e = blockIdx.x * 256 + threadIdx.x;     // TOTAL_E exact
    int type = e / M_EDGES;
    int src = edges[(size_t)e * 2];
    int tgt = edges[(size_t)e * 2 + 1];
    int p = atomicAdd(cursor + type * N_NODES + tgt, 1);
    packed[p] = (unsigned)src | ((unsigned)posl[e] << 17);   // type implicit in segment
}

// ---- fp16 NT GEMM: prop(M_PAD x 256) = A16 * B_t^T + b_t ------------------
__global__ __launch_bounds__(512, 4) void gemm_f16(
        const _Float16* __restrict__ Ap,
        const _Float16* __restrict__ Bt,
        const float* __restrict__ bias,
        _Float16* __restrict__ prop)
{
    __shared__ __align__(16) _Float16 sA[128 * 64];
    __shared__ __align__(16) _Float16 sB[256 * 64];
    const int tid  = threadIdx.x;
    const int lane = tid & 63;
    const int wid  = tid >> 6;
    const int wr   = wid >> 2;   // 0..1
    const int wc   = wid & 3;    // 0..3
    const size_t m0 = (size_t)blockIdx.x * 128;

    f32x4 acc[4][4];
    #pragma unroll
    for (int m = 0; m < 4; ++m)
        #pragma unroll
        for (int n = 0; n < 4; ++n)
            acc[m][n] = (f32x4){0.f, 0.f, 0.f, 0.f};

    const int sub = lane >> 3;        // row within 8-row chunk
    const int bib = (lane & 7) << 4;  // byte within 128B row

    for (int kk = 0; kk < 4; ++kk){
        #pragma unroll
        for (int ci = 0; ci < 6; ++ci){
            int c = wid * 6 + ci;
            const _Float16* grow;
            _Float16* lrow;
            int r;
            if (c < 16){
                r = (c << 3) + sub;                     // 0..127
                grow = Ap + (m0 + (size_t)r) * 256;
                lrow = sA + r * 64;
            } else {
                r = ((c - 16) << 3) + sub;              // 0..255
                grow = Bt + (size_t)r * 256;
                lrow = sB + r * 64;
            }
            uint4 v = *(const uint4*)((const char*)grow + (kk << 7) + bib);
            int sw = bib ^ ((r & 7) << 4);
            *(uint4*)((char*)lrow + sw) = v;
        }
        __syncthreads();

        #pragma unroll
        for (int ks = 0; ks < 2; ++ks){
            int slot = (ks << 6) + ((lane >> 4) << 4);
            f16x8 af[4];
            #pragma unroll
            for (int m = 0; m < 4; ++m){
                int rA = (wr << 6) + (m << 4) + (lane & 15);
                af[m] = *(const f16x8*)((const char*)sA + rA * 128 + (slot ^ ((rA & 7) << 4)));
            }
            #pragma unroll
            for (int n = 0; n < 4; ++n){
                int rB = (wc << 6) + (n << 4) + (lane & 15);
                f16x8 bfr = *(const f16x8*)((const char*)sB + rB * 128 + (slot ^ ((rB & 7) << 4)));
                #pragma unroll
                for (int m = 0; m < 4; ++m)
                    acc[m][n] = __builtin_amdgcn_mfma_f32_16x16x32_f16(af[m], bfr, acc[m][n], 0, 0, 0);
            }
        }
        __syncthreads();
    }

    #pragma unroll
    for (int n = 0; n < 4; ++n){
        int col = (wc << 6) + (n << 4) + (lane & 15);
        float bv = bias[col];
        #pragma unroll
        for (int m = 0; m < 4; ++m){
            int rowb = (int)m0 + (wr << 6) + (m << 4) + ((lane >> 4) << 2);
            #pragma unroll
            for (int j = 0; j < 4; ++j)
                prop[(size_t)(rowb + j) * DIM + col] = (_Float16)(acc[m][n][j] + bv);
        }
    }
}

// ---- per-type aggregation, L3-resident prop -------------------------------
// t==0: plain store (initializes out). 0<t<5: RMW add. t==5: RMW + divide.
__global__ void aggregate(const _Float16* __restrict__ prop, const _Float16* __restrict__ gate,
                          const unsigned* __restrict__ packed,
                          const int* __restrict__ off_, const int* __restrict__ cnt,
                          int t, float* __restrict__ out)
{
    int tgt  = blockIdx.x * 4 + (threadIdx.x >> 6);
    int lane = threadIdx.x & 63;
    int slot = t * N_NODES + tgt;
    int n    = cnt[slot];
    int base = off_[slot];
    float4 a = make_float4(0.f, 0.f, 0.f, 0.f);
    for (int c0 = 0; c0 < n; c0 += 64){
        int m = n - c0; if (m > 64) m = 64;
        unsigned wv = (lane < m) ? packed[base + c0 + lane] : 0u;
        for (int e = 0; e < m; ++e){
            unsigned w = (unsigned)__builtin_amdgcn_readlane((int)wv, e);
            int src = (int)(w & 0x1FFFFu);
            int pz  = (int)(w >> 17);
            f16x4 pv = *(const f16x4*)(prop + (size_t)src * 256 + lane * 4);
            f16x4 gv = *(const f16x4*)(gate + (size_t)pz  * 256 + lane * 4);
            a.x += (float)pv[0] * (float)gv[0];
            a.y += (float)pv[1] * (float)gv[1];
            a.z += (float)pv[2] * (float)gv[2];
            a.w += (float)pv[3] * (float)gv[3];
        }
    }
    float4* op = (float4*)(out + (size_t)tgt * DIM) + lane;
    if (t == 0){
        *op = a;
    } else if (t < NTYPES - 1){
        if (n){
            float4 c = *op;
            c.x += a.x; c.y += a.y; c.z += a.z; c.w += a.w;
            *op = c;
        }
    } else {
        int deg = 0;
        #pragma unroll
        for (int i = 0; i < NTYPES; ++i) deg += cnt[i * N_NODES + tgt];
        float inv = ((deg == 0) ? 1.0f : (float)deg) + 1e-8f;
        float4 c = *op;
        c.x = (c.x + a.x) / inv;
        c.y = (c.y + a.y) / inv;
        c.z = (c.z + a.z) / inv;
        c.w = (c.w + a.w) / inv;
        *op = c;
    }
}

extern "C" void kernel_launch(void* const* d_in, const int* in_sizes, int n_in,
                              void* d_out, int out_size, void* d_ws, size_t ws_size,
                              hipStream_t stream)
{
    const float* x     = (const float*)d_in[0];
    const float* W     = (const float*)d_in[1];
    const float* b     = (const float*)d_in[2];
    const float* Wp    = (const float*)d_in[3];
    const float* bp    = (const float*)d_in[4];
    const int*   edges = (const int*)d_in[5];
    const int*   posl  = (const int*)d_in[6];
    float* out = (float*)d_out;

    char* ws = (char*)d_ws;
    size_t o = 0;
    auto alloc = [&](size_t bytes){ void* p = ws + o; o += (bytes + 255) & ~(size_t)255; return p; };

    _Float16* Ap   = (_Float16*)alloc((size_t)M_PAD * 256 * 2);
    _Float16* prop = (_Float16*)alloc((size_t)M_PAD * 256 * 2);
    _Float16* Bp   = (_Float16*)alloc((size_t)NTYPES * 256 * 256 * 2);
    _Float16* gate = (_Float16*)alloc((size_t)512 * 256 * 2);
    int* cnt    = (int*)alloc((size_t)NCNT * 4);
    int* off_   = (int*)alloc((size_t)NCNT * 4);
    int* cursor = (int*)alloc((size_t)NCNT * 4);
    unsigned* packed = (unsigned*)alloc((size_t)TOTAL_E * 4);
    int* bsum   = (int*)alloc(4096);
    int* ssum   = (int*)alloc(4096);

    hipMemsetAsync(cnt, 0, (size_t)NCNT * 4, stream);

    build_a16<<<12512, 256, 0, stream>>>(x, Ap);
    build_b16<<<192, 256, 0, stream>>>(W, Bp);
    build_gating<<<512, 256, 0, stream>>>(Wp, bp, gate);
    hist_kernel<<<9375, 256, 0, stream>>>(edges, cnt);
    scan1_kernel<<<SCAN_BLKS, 256, 0, stream>>>(cnt, off_, bsum);
    scan2_kernel<<<1, 256, 0, stream>>>(bsum, ssum);
    scan3_kernel<<<2344, 256, 0, stream>>>(off_, ssum, cursor);
    scatter_kernel<<<9375, 256, 0, stream>>>(edges, posl, cursor, packed);

    for (int t = 0; t < NTYPES; ++t){
        gemm_f16<<<782, 512, 0, stream>>>(Ap, Bp + (size_t)t * 256 * 256,
                                          b + (size_t)t * 256, prop);
        aggregate<<<25000, 256, 0, stream>>>(prop, gate, packed, off_, cnt, t, out);
    }
}

// Round 4
// 922.324 us; speedup vs baseline: 1.3993x; 1.0900x over previous
//
#include <hip/hip_runtime.h>
#include <cstdint>
#include <cstddef>

#define N_NODES   100000
#define M_PAD     100096   // 782 * 128
#define DIM       256
#define NTYPES    6
#define M_EDGES   400000
#define TOTAL_E   2400000
#define HALF_E    1200000
#define QUART_E   600000
#define NCNT      200000   // 2 halves * N_NODES
#define SCAN_BLKS 196      // ceil(NCNT/1024)

typedef _Float16 f16x8 __attribute__((ext_vector_type(8)));
typedef _Float16 f16x4 __attribute__((ext_vector_type(4)));
typedef float    f32x4 __attribute__((ext_vector_type(4)));

// ---- A16 = fp16(X), rows padded to M_PAD ----------------------------------
__global__ void build_a16(const float* __restrict__ x, _Float16* __restrict__ Ap){
    int tid = blockIdx.x * 256 + threadIdx.x;   // M_PAD*256/8 threads exact
    int idx = tid << 3;
    int row = idx >> 8;
    int k   = idx & 255;
    f16x8 h;
    if (row < N_NODES){
        const float* px = x + (size_t)row * DIM + k;
        float4 v0 = *(const float4*)px;
        float4 v1 = *(const float4*)(px + 4);
        h[0] = (_Float16)v0.x; h[1] = (_Float16)v0.y; h[2] = (_Float16)v0.z; h[3] = (_Float16)v0.w;
        h[4] = (_Float16)v1.x; h[5] = (_Float16)v1.y; h[6] = (_Float16)v1.z; h[7] = (_Float16)v1.w;
    } else {
        #pragma unroll
        for (int j = 0; j < 8; ++j) h[j] = (_Float16)0.f;
    }
    *(f16x8*)(Ap + (size_t)row * 256 + k) = h;
}

// ---- B16 = fp16(W)  (1536 x 256) ------------------------------------------
__global__ void build_b16(const float* __restrict__ W, _Float16* __restrict__ Bp){
    int tid = blockIdx.x * 256 + threadIdx.x;   // 1536*256/8 threads exact
    int idx = tid << 3;
    const float* pw = W + idx;
    float4 v0 = *(const float4*)pw;
    float4 v1 = *(const float4*)(pw + 4);
    f16x8 h;
    h[0] = (_Float16)v0.x; h[1] = (_Float16)v0.y; h[2] = (_Float16)v0.z; h[3] = (_Float16)v0.w;
    h[4] = (_Float16)v1.x; h[5] = (_Float16)v1.y; h[6] = (_Float16)v1.z; h[7] = (_Float16)v1.w;
    *(f16x8*)(Bp + idx) = h;
}

// ---- gating table 2*sigmoid(posemb @ Wp^T + bp), fp64 trig, fp16 out ------
__global__ void build_gating(const float* __restrict__ Wp, const float* __restrict__ bp,
                             _Float16* __restrict__ gate){
    __shared__ float semb[256];
    int p = blockIdx.x;     // 0..511
    int t = threadIdx.x;    // 0..255
    if (t < 127){
        double invf = exp(-log(10000.0) * (2.0 * t) / 254.0);
        double a = (double)p * invf;
        semb[t]       = (float)sin(a);
        semb[t + 127] = (float)cos(a);
    } else if (t >= 254){
        semb[t] = 0.0f;
    }
    __syncthreads();
    float z = bp[t];
    const float* wr = Wp + (size_t)t * 256;
    #pragma unroll 4
    for (int kq = 0; kq < 256; ++kq) z += semb[kq] * wr[kq];
    gate[(size_t)p * 256 + t] = (_Float16)(2.0f / (1.0f + expf(-z)));
}

// ---- CSR over (half,tgt): histogram -> scan -> scatter, ILP-4 -------------
__global__ void hist_kernel(const int* __restrict__ edges, int* __restrict__ cnt){
    int t0 = blockIdx.x * 256 + threadIdx.x;
    if (t0 >= QUART_E) return;
    #pragma unroll
    for (int j = 0; j < 4; ++j){
        int e = t0 + j * QUART_E;
        int half = e / HALF_E;
        int tgt = edges[(size_t)e * 2 + 1];
        atomicAdd(cnt + half * N_NODES + tgt, 1);
    }
}

__global__ void scan1_kernel(const int* __restrict__ cnt, int* __restrict__ partial,
                             int* __restrict__ bsum){
    __shared__ int lds[256];
    int t = threadIdx.x;
    int base = blockIdx.x * 1024 + t * 4;
    int v[4]; int s = 0;
    #pragma unroll
    for (int j = 0; j < 4; ++j){ int idx = base + j; v[j] = (idx < NCNT) ? cnt[idx] : 0; s += v[j]; }
    lds[t] = s; __syncthreads();
    for (int d = 1; d < 256; d <<= 1){
        int xv = (t >= d) ? lds[t - d] : 0;
        __syncthreads();
        lds[t] += xv;
        __syncthreads();
    }
    int run = (t > 0) ? lds[t - 1] : 0;
    #pragma unroll
    for (int j = 0; j < 4; ++j){ int idx = base + j; if (idx < NCNT) partial[idx] = run; run += v[j]; }
    if (t == 255) bsum[blockIdx.x] = run;
}

__global__ void scan2_kernel(const int* __restrict__ bsum, int* __restrict__ ssum){
    __shared__ int lds[256];
    int t = threadIdx.x;
    int v = (t < SCAN_BLKS) ? bsum[t] : 0;
    lds[t] = v; __syncthreads();
    for (int d = 1; d < 256; d <<= 1){
        int xv = (t >= d) ? lds[t - d] : 0;
        __syncthreads();
        lds[t] += xv;
        __syncthreads();
    }
    ssum[t] = (t > 0) ? lds[t - 1] : 0;
}

__global__ void scan3_kernel(int* __restrict__ off_, const int* __restrict__ ssum,
                             int* __restrict__ cursor){
    int idx = blockIdx.x * 256 + threadIdx.x;
    if (idx >= NCNT) return;
    int vv = off_[idx] + ssum[idx >> 10];
    off_[idx] = vv;
    cursor[idx] = vv;
}

__global__ void scatter_kernel(const int* __restrict__ edges, const int* __restrict__ posl,
                               int* __restrict__ cursor, unsigned* __restrict__ packed){
    int t0 = blockIdx.x * 256 + threadIdx.x;
    if (t0 >= QUART_E) return;
    #pragma unroll
    for (int j = 0; j < 4; ++j){
        int e = t0 + j * QUART_E;
        int type = e / M_EDGES;
        int half = e / HALF_E;
        int typ3 = type - half * 3;
        int2 ed = *(const int2*)(edges + (size_t)e * 2);
        int p = atomicAdd(cursor + half * N_NODES + ed.y, 1);
        packed[p] = (unsigned)ed.x | ((unsigned)posl[e] << 17) | ((unsigned)typ3 << 26);
    }
}

// ---- fp16 NT GEMM trio: prop_t = A16 * B_t^T + b_t for 3 types ------------
__global__ __launch_bounds__(512, 4) void gemm_f16(
        const _Float16* __restrict__ Ap,
        const _Float16* __restrict__ Bbase,
        const float* __restrict__ bbase,
        _Float16* __restrict__ prop)
{
    __shared__ __align__(16) _Float16 sA[128 * 64];
    __shared__ __align__(16) _Float16 sB[256 * 64];
    const int bid  = blockIdx.x;
    const int rp   = bid / 3;
    const int t    = bid - rp * 3;
    const int tid  = threadIdx.x;
    const int lane = tid & 63;
    const int wid  = tid >> 6;
    const int wr   = wid >> 2;   // 0..1
    const int wc   = wid & 3;    // 0..3
    const size_t m0 = (size_t)rp * 128;
    const _Float16* Bt = Bbase + (size_t)t * 256 * 256;

    f32x4 acc[4][4];
    #pragma unroll
    for (int m = 0; m < 4; ++m)
        #pragma unroll
        for (int n = 0; n < 4; ++n)
            acc[m][n] = (f32x4){0.f, 0.f, 0.f, 0.f};

    const int sub = lane >> 3;        // row within 8-row chunk
    const int bib = (lane & 7) << 4;  // byte within 128B row

    for (int kk = 0; kk < 4; ++kk){
        #pragma unroll
        for (int ci = 0; ci < 6; ++ci){
            int c = wid * 6 + ci;
            const _Float16* grow;
            _Float16* lrow;
            int r;
            if (c < 16){
                r = (c << 3) + sub;                     // 0..127
                grow = Ap + (m0 + (size_t)r) * 256;
                lrow = sA + r * 64;
            } else {
                r = ((c - 16) << 3) + sub;              // 0..255
                grow = Bt + (size_t)r * 256;
                lrow = sB + r * 64;
            }
            uint4 v = *(const uint4*)((const char*)grow + (kk << 7) + bib);
            int sw = bib ^ ((r & 7) << 4);
            *(uint4*)((char*)lrow + sw) = v;
        }
        __syncthreads();

        #pragma unroll
        for (int ks = 0; ks < 2; ++ks){
            int slot = (ks << 6) + ((lane >> 4) << 4);
            f16x8 af[4];
            #pragma unroll
            for (int m = 0; m < 4; ++m){
                int rA = (wr << 6) + (m << 4) + (lane & 15);
                af[m] = *(const f16x8*)((const char*)sA + rA * 128 + (slot ^ ((rA & 7) << 4)));
            }
            #pragma unroll
            for (int n = 0; n < 4; ++n){
                int rB = (wc << 6) + (n << 4) + (lane & 15);
                f16x8 bfr = *(const f16x8*)((const char*)sB + rB * 128 + (slot ^ ((rB & 7) << 4)));
                #pragma unroll
                for (int m = 0; m < 4; ++m)
                    acc[m][n] = __builtin_amdgcn_mfma_f32_16x16x32_f16(af[m], bfr, acc[m][n], 0, 0, 0);
            }
        }
        __syncthreads();
    }

    _Float16* Ct = prop + (size_t)t * M_PAD * 256;
    #pragma unroll
    for (int n = 0; n < 4; ++n){
        int col = (wc << 6) + (n << 4) + (lane & 15);
        float bv = bbase[(size_t)t * 256 + col];
        #pragma unroll
        for (int m = 0; m < 4; ++m){
            int rowb = (int)m0 + (wr << 6) + (m << 4) + ((lane >> 4) << 2);
            #pragma unroll
            for (int j = 0; j < 4; ++j)
                Ct[(size_t)(rowb + j) * DIM + col] = (_Float16)(acc[m][n][j] + bv);
        }
    }
}

// ---- half aggregation: 3 L3-resident props, one wave per target ------------
// h==0: plain store. h==1: RMW + divide by total degree.
__global__ void aggregate(const _Float16* __restrict__ prop, const _Float16* __restrict__ gate,
                          const unsigned* __restrict__ packed,
                          const int* __restrict__ off_, const int* __restrict__ cnt,
                          int h, float* __restrict__ out)
{
    int tgt  = blockIdx.x * 4 + (threadIdx.x >> 6);
    int lane = threadIdx.x & 63;
    int slot = h * N_NODES + tgt;
    int n    = cnt[slot];
    int base = off_[slot];
    float4 a = make_float4(0.f, 0.f, 0.f, 0.f);
    for (int c0 = 0; c0 < n; c0 += 64){
        int m = n - c0; if (m > 64) m = 64;
        unsigned wv = (lane < m) ? packed[base + c0 + lane] : 0u;
        for (int e = 0; e < m; ++e){
            unsigned w = (unsigned)__builtin_amdgcn_readlane((int)wv, e);
            int src  = (int)(w & 0x1FFFFu);
            int pz   = (int)((w >> 17) & 0x1FFu);
            int typ3 = (int)(w >> 26);
            f16x4 pv = *(const f16x4*)(prop + ((size_t)typ3 * M_PAD + (size_t)src) * 256 + lane * 4);
            f16x4 gv = *(const f16x4*)(gate + (size_t)pz * 256 + lane * 4);
            a.x += (float)pv[0] * (float)gv[0];
            a.y += (float)pv[1] * (float)gv[1];
            a.z += (float)pv[2] * (float)gv[2];
            a.w += (float)pv[3] * (float)gv[3];
        }
    }
    float4* op = (float4*)(out + (size_t)tgt * DIM) + lane;
    if (h == 0){
        *op = a;
    } else {
        int deg = cnt[tgt] + cnt[N_NODES + tgt];
        float inv = ((deg == 0) ? 1.0f : (float)deg) + 1e-8f;
        float4 c = *op;
        c.x = (c.x + a.x) / inv;
        c.y = (c.y + a.y) / inv;
        c.z = (c.z + a.z) / inv;
        c.w = (c.w + a.w) / inv;
        *op = c;
    }
}

extern "C" void kernel_launch(void* const* d_in, const int* in_sizes, int n_in,
                              void* d_out, int out_size, void* d_ws, size_t ws_size,
                              hipStream_t stream)
{
    const float* x     = (const float*)d_in[0];
    const float* W     = (const float*)d_in[1];
    const float* b     = (const float*)d_in[2];
    const float* Wp    = (const float*)d_in[3];
    const float* bp    = (const float*)d_in[4];
    const int*   edges = (const int*)d_in[5];
    const int*   posl  = (const int*)d_in[6];
    float* out = (float*)d_out;

    char* ws = (char*)d_ws;
    size_t o = 0;
    auto alloc = [&](size_t bytes){ void* p = ws + o; o += (bytes + 255) & ~(size_t)255; return p; };

    _Float16* Ap   = (_Float16*)alloc((size_t)M_PAD * 256 * 2);
    _Float16* prop = (_Float16*)alloc((size_t)3 * M_PAD * 256 * 2);
    _Float16* Bp   = (_Float16*)alloc((size_t)NTYPES * 256 * 256 * 2);
    _Float16* gate = (_Float16*)alloc((size_t)512 * 256 * 2);
    int* cnt    = (int*)alloc((size_t)NCNT * 4);
    int* off_   = (int*)alloc((size_t)NCNT * 4);
    int* cursor = (int*)alloc((size_t)NCNT * 4);
    unsigned* packed = (unsigned*)alloc((size_t)TOTAL_E * 4);
    int* bsum   = (int*)alloc(4096);
    int* ssum   = (int*)alloc(4096);

    hipMemsetAsync(cnt, 0, (size_t)NCNT * 4, stream);

    build_a16<<<12512, 256, 0, stream>>>(x, Ap);
    build_b16<<<192, 256, 0, stream>>>(W, Bp);
    build_gating<<<512, 256, 0, stream>>>(Wp, bp, gate);
    hist_kernel<<<2344, 256, 0, stream>>>(edges, cnt);
    scan1_kernel<<<SCAN_BLKS, 256, 0, stream>>>(cnt, off_, bsum);
    scan2_kernel<<<1, 256, 0, stream>>>(bsum, ssum);
    scan3_kernel<<<782, 256, 0, stream>>>(off_, ssum, cursor);
    scatter_kernel<<<2344, 256, 0, stream>>>(edges, posl, cursor, packed);

    for (int h = 0; h < 2; ++h){
        gemm_f16<<<2346, 512, 0, stream>>>(Ap, Bp + (size_t)h * 3 * 256 * 256,
                                           b + (size_t)h * 3 * 256, prop);
        aggregate<<<25000, 256, 0, stream>>>(prop, gate, packed, off_, cnt, h, out);
    }
}